// Round 8
// baseline (142.201 us; speedup 1.0000x reference)
//
#include <hip/hip_runtime.h>
#include <hip/hip_bf16.h>
#include <math.h>

#define NDIM 16
#define HDIM 128
#define BATCH 256
#define EPS_D 1e-6f

// ---- Kernel 1: metric = sym(MLP(points)) + eps*I, rW1 block projections,
//      G zero-init, and packed+scaled christoffel weights for SMEM access.
//      cwPack[h] = {S*cW1[0][h], S*cW1[1][h], S*cW1[2][h], S*cb1[h]}, S=2log2e
__global__ __launch_bounds__(256) void metric_proj_kernel(
    const float* __restrict__ points,
    const float* __restrict__ mW1, const float* __restrict__ mb1,
    const float* __restrict__ mW2, const float* __restrict__ mb2,
    const float* __restrict__ rW1, const float* __restrict__ rb1,
    const float* __restrict__ cW1, const float* __restrict__ cb1,
    const float* __restrict__ cW2,
    float* __restrict__ metric,
    float* __restrict__ A1, float* __restrict__ Mi, float* __restrict__ Mj,
    float* __restrict__ G, float4* __restrict__ cwPack,
    float* __restrict__ w2c) {
  int b = blockIdx.x;
  int t = threadIdx.x;  // 0..255
  __shared__ float p[16];
  __shared__ float mh[128];
  __shared__ float raw[256];
  __shared__ float M[256];
  G[b * 256 + t] = 0.f;
  if (t < 128) {  // all blocks write identical values (idempotent)
    const float S = 2.8853900817779268f;  // 2 * log2(e)
    cwPack[t] = make_float4(S * cW1[t], S * cW1[128 + t], S * cW1[256 + t],
                            S * cb1[t]);
    w2c[t] = cW2[t];
  }
  if (t < 16) p[t] = points[b * 16 + t];
  __syncthreads();
  if (t < 128) {
    float acc = mb1[t];
#pragma unroll
    for (int k = 0; k < 16; ++k) acc = fmaf(p[k], mW1[k * 128 + t], acc);
    mh[t] = fmaxf(acc, 0.f);
  }
  __syncthreads();
  {
    float acc = mb2[t];
#pragma unroll 8
    for (int h = 0; h < 128; ++h) acc = fmaf(mh[h], mW2[h * 256 + t], acc);
    raw[t] = acc;
  }
  __syncthreads();
  {
    int i = t >> 4, j = t & 15;
    float v = 0.5f * (raw[i * 16 + j] + raw[j * 16 + i]);
    if (i == j) v += EPS_D;
    M[t] = v;
    metric[b * 256 + t] = v;
  }
  __syncthreads();
  {
    int h = t;
    float wB[16], wC[16];
#pragma unroll
    for (int c = 0; c < 16; ++c) {
      wB[c] = rW1[(16 + c) * 256 + h];
      wC[c] = rW1[(32 + c) * 256 + h];
    }
    float a = rb1[h];
#pragma unroll
    for (int r = 0; r < 16; ++r) a = fmaf(p[r], rW1[r * 256 + h], a);
    A1[b * 256 + h] = a;
#pragma unroll 2
    for (int i = 0; i < 16; ++i) {
      float mi = 0.f, mj = 0.f;
#pragma unroll
      for (int c = 0; c < 16; ++c) {
        float m = M[i * 16 + c];
        mi = fmaf(m, wB[c], mi);
        mj = fmaf(m, wC[c], mj);
      }
      Mi[(b * 16 + i) * 256 + h] = mi;
      Mj[(b * 16 + i) * 256 + h] = mj;
    }
  }
}

// ---- Kernel 2: fused christoffel MLP + ricci layer-1 relu + i-reduction ----
// One 128-thread block (2 waves) per (b,i). Phase 1: lane l of wave w owns
// triples jk0 = 128w+l and jk0+64 (same k, j differs by 4). Weights are read
// from GLOBAL with wave-uniform index -> compiler emits s_load (SMEM/scalar
// cache), so the h-loop issues ZERO LDS instructions. tanh via
// 1 - 2/(exp2(pre)+1) with 2log2e pre-folded into cwPack; 2 trans/tanh on the
// per-SIMD trans unit. Phase 2 after barrier: hidden pair (t, t+128).
__global__ __launch_bounds__(128, 8) void chr_kernel(
    const float* __restrict__ metric,
    const float4* __restrict__ cwPack, const float* __restrict__ w2c,
    const float* __restrict__ cb2,
    const float* __restrict__ rW1,
    const float* __restrict__ A1, const float* __restrict__ Mi,
    const float* __restrict__ Mj,
    float* __restrict__ G) {
  int bi = blockIdx.x;         // b*16 + i
  int b = bi >> 4, i = bi & 15;
  int t = threadIdx.x;         // 0..127
  int w = t >> 6, l = t & 63;  // wave, lane
  __shared__ float M[256];
  __shared__ float chf[256];
  M[t] = metric[b * 256 + t];
  M[t + 128] = metric[b * 256 + t + 128];
  __syncthreads();

  // ---- phase 1: triples jk0 = 128w+l, jk1 = jk0+64 ----
  {
    int jk0 = w * 128 + l;
    int j0 = jk0 >> 4, k0 = jk0 & 15;
    float x00 = M[i * 16 + j0], x01 = M[i * 16 + j0 + 4];
    float x10 = M[jk0], x11 = M[jk0 + 64];
    float x2s = M[k0 * 16 + i];
    float acc0 = 0.f, acc1 = 0.f;
#pragma unroll 4
    for (int h = 0; h < 128; ++h) {
      float4 Q = cwPack[h];   // uniform -> s_load_dwordx4
      float wh = w2c[h];      // uniform -> s_load
      float bb = fmaf(x2s, Q.z, Q.w);
      float p0 = fmaf(x00, Q.x, fmaf(x10, Q.y, bb));
      float p1 = fmaf(x01, Q.x, fmaf(x11, Q.y, bb));
      float e0 = __builtin_amdgcn_exp2f(p0);
      float e1 = __builtin_amdgcn_exp2f(p1);
      float r0 = __builtin_amdgcn_rcpf(e0 + 1.f);
      float r1 = __builtin_amdgcn_rcpf(e1 + 1.f);
      acc0 = fmaf(wh, fmaf(-2.f, r0, 1.f), acc0);
      acc1 = fmaf(wh, fmaf(-2.f, r1, 1.f), acc1);
    }
    float c2 = cb2[0];
    chf[jk0] = acc0 + c2;
    chf[jk0 + 64] = acc1 + c2;
  }
  __syncthreads();  // phase 2 reads BOTH waves' ch values

  // ---- phase 2: hidden-unit pair (t, t+128) per thread ----
  {
    int h0 = t, h1 = t + 128;
    float rc0[16], rc1[16];
#pragma unroll
    for (int kk = 0; kk < 16; ++kk) {
      const float* row = rW1 + (48 + kk) * 256;
      rc0[kk] = row[h0];
      rc1[kk] = row[h1];
    }
    const float* A1b = A1 + b * 256;
    const float* Mib = Mi + bi * 256;
    float base0 = A1b[h0] + Mib[h0];
    float base1 = A1b[h1] + Mib[h1];
    float hacc0 = 0.f, hacc1 = 0.f;
    const float4* ch4 = (const float4*)chf;
    for (int jj = 0; jj < 16; ++jj) {
      float4 c0 = ch4[jj * 4 + 0];
      float4 c1 = ch4[jj * 4 + 1];
      float4 c2v = ch4[jj * 4 + 2];
      float4 c3 = ch4[jj * 4 + 3];
      float cc[16] = {c0.x, c0.y, c0.z, c0.w, c1.x, c1.y, c1.z, c1.w,
                      c2v.x, c2v.y, c2v.z, c2v.w, c3.x, c3.y, c3.z, c3.w};
      const float* Mjr = Mj + (b * 16 + jj) * 256;
      float cp0 = base0 + Mjr[h0];
      float cp1 = base1 + Mjr[h1];
#pragma unroll
      for (int kk = 0; kk < 16; ++kk) {
        cp0 = fmaf(cc[kk], rc0[kk], cp0);
        cp1 = fmaf(cc[kk], rc1[kk], cp1);
      }
      hacc0 += fmaxf(cp0, 0.f);
      hacc1 += fmaxf(cp1, 0.f);
    }
    atomicAdd(&G[b * 256 + h0], hacc0);
    atomicAdd(&G[b * 256 + h1], hacc1);
  }
}

// ---- Kernel 3: linear layer 2 on G, symmetrize, scale ----------------------
__global__ __launch_bounds__(256) void final_kernel(
    const float* __restrict__ G,
    const float* __restrict__ rW2, const float* __restrict__ rb2,
    float* __restrict__ out) {
  int b = blockIdx.x;
  int t = threadIdx.x;
  __shared__ float4 Gs[64];
  __shared__ float T[256];
  if (t < 64) Gs[t] = ((const float4*)(G + b * 256))[t];
  __syncthreads();
  float acc = 256.f * rb2[t];
#pragma unroll 4
  for (int h4 = 0; h4 < 64; ++h4) {
    float4 gg = Gs[h4];
    acc = fmaf(gg.x, rW2[(h4 * 4 + 0) * 256 + t], acc);
    acc = fmaf(gg.y, rW2[(h4 * 4 + 1) * 256 + t], acc);
    acc = fmaf(gg.z, rW2[(h4 * 4 + 2) * 256 + t], acc);
    acc = fmaf(gg.w, rW2[(h4 * 4 + 3) * 256 + t], acc);
  }
  T[t] = acc * (1.f / 256.f);
  __syncthreads();
  int k = t >> 4, lcol = t & 15;
  out[b * 256 + t] = 0.5f * (T[k * 16 + lcol] + T[lcol * 16 + k]);
}

extern "C" void kernel_launch(void* const* d_in, const int* in_sizes, int n_in,
                              void* d_out, int out_size, void* d_ws, size_t ws_size,
                              hipStream_t stream) {
  const float* points = (const float*)d_in[0];
  const float* mW1 = (const float*)d_in[1];
  const float* mb1 = (const float*)d_in[2];
  const float* mW2 = (const float*)d_in[3];
  const float* mb2 = (const float*)d_in[4];
  const float* cW1 = (const float*)d_in[5];
  const float* cb1 = (const float*)d_in[6];
  const float* cW2 = (const float*)d_in[7];
  const float* cb2 = (const float*)d_in[8];
  const float* rW1 = (const float*)d_in[9];
  const float* rb1 = (const float*)d_in[10];
  const float* rW2 = (const float*)d_in[11];
  const float* rb2 = (const float*)d_in[12];
  float* out = (float*)d_out;

  float* ws = (float*)d_ws;
  float* metric = ws;                 // 65536
  float* A1 = metric + 65536;         // 65536
  float* Mi = A1 + 65536;             // 1048576
  float* Mj = Mi + 1048576;           // 1048576
  float* G = Mj + 1048576;            // 65536
  float* cwPackF = G + 65536;         // 512 (128 x float4)
  float* w2c = cwPackF + 512;         // 128

  metric_proj_kernel<<<BATCH, 256, 0, stream>>>(
      points, mW1, mb1, mW2, mb2, rW1, rb1, cW1, cb1, cW2,
      metric, A1, Mi, Mj, G, (float4*)cwPackF, w2c);
  chr_kernel<<<BATCH * NDIM, 128, 0, stream>>>(metric, (const float4*)cwPackF,
                                               w2c, cb2, rW1, A1, Mi, Mj, G);
  final_kernel<<<BATCH, 256, 0, stream>>>(G, rW2, rb2, out);
}

// Round 9
// 139.975 us; speedup vs baseline: 1.0159x; 1.0159x over previous
//
#include <hip/hip_runtime.h>
#include <hip/hip_bf16.h>
#include <math.h>

#define NDIM 16
#define HDIM 128
#define BATCH 256
#define EPS_D 1e-6f

#define SSCALE 2.8853900817779268f   // 2*log2(e)
#define SCLAMP 23.0829f              // just under 8*SSCALE
#define KIDX 11.0903543f             // 512 / (16*SSCALE)
#define NEXP 44                      // h in [0,NEXP) via exp, rest via PWL

// ---- Kernel 1: metric = sym(MLP(points)) + eps*I, rW1 block projections,
//      G zero-init, packed scaled christoffel weights (SMEM path), and the
//      scaled-domain PWL tanh table (512 segments over s in [-8S, 8S]).
__global__ __launch_bounds__(256) void metric_proj_kernel(
    const float* __restrict__ points,
    const float* __restrict__ mW1, const float* __restrict__ mb1,
    const float* __restrict__ mW2, const float* __restrict__ mb2,
    const float* __restrict__ rW1, const float* __restrict__ rb1,
    const float* __restrict__ cW1, const float* __restrict__ cb1,
    const float* __restrict__ cW2,
    float* __restrict__ metric,
    float* __restrict__ A1, float* __restrict__ Mi, float* __restrict__ Mj,
    float* __restrict__ G, float4* __restrict__ cwPack,
    float* __restrict__ w2c, float* __restrict__ tanhtab) {
  int b = blockIdx.x;
  int t = threadIdx.x;  // 0..255
  __shared__ float p[16];
  __shared__ float mh[128];
  __shared__ float raw[256];
  __shared__ float M[256];
  G[b * 256 + t] = 0.f;
  if (t < 128) {  // idempotent across blocks
    cwPack[t] = make_float4(SSCALE * cW1[t], SSCALE * cW1[128 + t],
                            SSCALE * cW1[256 + t], SSCALE * cb1[t]);
    w2c[t] = cW2[t];
  }
  {  // PWL table entries t and t+256: tanh vs the SCALED preactivation s
    int e = t;
#pragma unroll
    for (int m = 0; m < 2; ++m) {
      float x0 = (e - 256) * 0.03125f;          // x-domain left edge
      float y0 = tanhf(x0);
      float y1 = tanhf(x0 + 0.03125f);
      float slope_s = (y1 - y0) / (SSCALE * 0.03125f);
      float s0 = SSCALE * x0;
      tanhtab[e * 2] = slope_s;
      tanhtab[e * 2 + 1] = fmaf(-slope_s, s0, y0);
      e += 256;
    }
  }
  if (t < 16) p[t] = points[b * 16 + t];
  __syncthreads();
  if (t < 128) {
    float acc = mb1[t];
#pragma unroll
    for (int k = 0; k < 16; ++k) acc = fmaf(p[k], mW1[k * 128 + t], acc);
    mh[t] = fmaxf(acc, 0.f);
  }
  __syncthreads();
  {
    float acc = mb2[t];
#pragma unroll 8
    for (int h = 0; h < 128; ++h) acc = fmaf(mh[h], mW2[h * 256 + t], acc);
    raw[t] = acc;
  }
  __syncthreads();
  {
    int i = t >> 4, j = t & 15;
    float v = 0.5f * (raw[i * 16 + j] + raw[j * 16 + i]);
    if (i == j) v += EPS_D;
    M[t] = v;
    metric[b * 256 + t] = v;
  }
  __syncthreads();
  {
    int h = t;
    float wB[16], wC[16];
#pragma unroll
    for (int c = 0; c < 16; ++c) {
      wB[c] = rW1[(16 + c) * 256 + h];
      wC[c] = rW1[(32 + c) * 256 + h];
    }
    float a = rb1[h];
#pragma unroll
    for (int r = 0; r < 16; ++r) a = fmaf(p[r], rW1[r * 256 + h], a);
    A1[b * 256 + h] = a;
#pragma unroll 2
    for (int i = 0; i < 16; ++i) {
      float mi = 0.f, mj = 0.f;
#pragma unroll
      for (int c = 0; c < 16; ++c) {
        float m = M[i * 16 + c];
        mi = fmaf(m, wB[c], mi);
        mj = fmaf(m, wC[c], mj);
      }
      Mi[(b * 16 + i) * 256 + h] = mi;
      Mj[(b * 16 + i) * 256 + h] = mj;
    }
  }
}

// ---- Kernel 2: fused christoffel MLP + ricci layer-1 relu + i-reduction ----
// One 128-thread block (2 waves) per (b,i); lane l of wave w owns triples
// jk0 = 128w+l and jk0+64. HYBRID tanh: h in [0,NEXP) via exp2+rcp
// (VALU+trans pipes), h in [NEXP,128) via scaled-domain PWL LDS gather
// (LDS pipe). Wave 0 runs exp-loop first, wave 1 PWL-loop first, so both
// pipe mixes coexist on every CU. Weights via wave-uniform global reads
// (s_load / scalar cache) -> zero LDS traffic beyond the gathers.
__global__ __launch_bounds__(128, 8) void chr_kernel(
    const float* __restrict__ metric,
    const float4* __restrict__ cwPack, const float* __restrict__ w2c,
    const float* __restrict__ cb2,
    const float* __restrict__ rW1,
    const float* __restrict__ A1, const float* __restrict__ Mi,
    const float* __restrict__ Mj,
    const float* __restrict__ tanhtab,
    float* __restrict__ G) {
  int bi = blockIdx.x;         // b*16 + i
  int b = bi >> 4, i = bi & 15;
  int t = threadIdx.x;         // 0..127
  int w = t >> 6, l = t & 63;  // wave, lane
  __shared__ float M[256];
  __shared__ float2 tab[512];
  __shared__ float chf[256];
  M[t] = metric[b * 256 + t];
  M[t + 128] = metric[b * 256 + t + 128];
  {
    const float4* tg = (const float4*)tanhtab;
    float4* tl = (float4*)tab;
    tl[t] = tg[t];
    tl[t + 128] = tg[t + 128];
  }
  __syncthreads();

  // ---- phase 1 ----
  {
    int jk0 = w * 128 + l;
    int j0 = jk0 >> 4, k0 = jk0 & 15;
    float x00 = M[i * 16 + j0], x01 = M[i * 16 + j0 + 4];
    float x10 = M[jk0], x11 = M[jk0 + 64];
    float x2s = M[k0 * 16 + i];
    float acc0 = 0.f, acc1 = 0.f;

    auto expLoop = [&]() {
#pragma unroll 4
      for (int h = 0; h < NEXP; ++h) {
        float4 Q = cwPack[h];
        float wh = w2c[h];
        float bb = fmaf(x2s, Q.z, Q.w);
        float p0 = fmaf(x00, Q.x, fmaf(x10, Q.y, bb));
        float p1 = fmaf(x01, Q.x, fmaf(x11, Q.y, bb));
        float e0 = __builtin_amdgcn_exp2f(p0);
        float e1 = __builtin_amdgcn_exp2f(p1);
        float r0 = __builtin_amdgcn_rcpf(e0 + 1.f);
        float r1 = __builtin_amdgcn_rcpf(e1 + 1.f);
        acc0 = fmaf(wh, fmaf(-2.f, r0, 1.f), acc0);
        acc1 = fmaf(wh, fmaf(-2.f, r1, 1.f), acc1);
      }
    };
    auto pwlLoop = [&]() {
#pragma unroll 4
      for (int h = NEXP; h < 128; ++h) {
        float4 Q = cwPack[h];
        float wh = w2c[h];
        float bb = fmaf(x2s, Q.z, Q.w);
        float p0 = fmaf(x00, Q.x, fmaf(x10, Q.y, bb));
        float p1 = fmaf(x01, Q.x, fmaf(x11, Q.y, bb));
        float c0 = __builtin_amdgcn_fmed3f(p0, -SCLAMP, SCLAMP);
        float c1 = __builtin_amdgcn_fmed3f(p1, -SCLAMP, SCLAMP);
        int i0 = (int)fmaf(c0, KIDX, 256.f);
        int i1 = (int)fmaf(c1, KIDX, 256.f);
        float2 s0 = tab[i0];
        float2 s1 = tab[i1];
        acc0 = fmaf(wh, fmaf(s0.x, c0, s0.y), acc0);
        acc1 = fmaf(wh, fmaf(s1.x, c1, s1.y), acc1);
      }
    };
    if (w == 0) { expLoop(); pwlLoop(); }
    else       { pwlLoop(); expLoop(); }

    float c2 = cb2[0];
    chf[jk0] = acc0 + c2;
    chf[jk0 + 64] = acc1 + c2;
  }
  __syncthreads();  // phase 2 reads BOTH waves' ch values

  // ---- phase 2: hidden-unit pair (t, t+128) per thread ----
  {
    int h0 = t, h1 = t + 128;
    float rc0[16], rc1[16];
#pragma unroll
    for (int kk = 0; kk < 16; ++kk) {
      const float* row = rW1 + (48 + kk) * 256;
      rc0[kk] = row[h0];
      rc1[kk] = row[h1];
    }
    const float* A1b = A1 + b * 256;
    const float* Mib = Mi + bi * 256;
    float base0 = A1b[h0] + Mib[h0];
    float base1 = A1b[h1] + Mib[h1];
    float hacc0 = 0.f, hacc1 = 0.f;
    const float4* ch4 = (const float4*)chf;
    for (int jj = 0; jj < 16; ++jj) {
      float4 c0 = ch4[jj * 4 + 0];
      float4 c1 = ch4[jj * 4 + 1];
      float4 c2v = ch4[jj * 4 + 2];
      float4 c3 = ch4[jj * 4 + 3];
      float cc[16] = {c0.x, c0.y, c0.z, c0.w, c1.x, c1.y, c1.z, c1.w,
                      c2v.x, c2v.y, c2v.z, c2v.w, c3.x, c3.y, c3.z, c3.w};
      const float* Mjr = Mj + (b * 16 + jj) * 256;
      float cp0 = base0 + Mjr[h0];
      float cp1 = base1 + Mjr[h1];
#pragma unroll
      for (int kk = 0; kk < 16; ++kk) {
        cp0 = fmaf(cc[kk], rc0[kk], cp0);
        cp1 = fmaf(cc[kk], rc1[kk], cp1);
      }
      hacc0 += fmaxf(cp0, 0.f);
      hacc1 += fmaxf(cp1, 0.f);
    }
    atomicAdd(&G[b * 256 + h0], hacc0);
    atomicAdd(&G[b * 256 + h1], hacc1);
  }
}

// ---- Kernel 3: linear layer 2 on G, symmetrize, scale ----------------------
__global__ __launch_bounds__(256) void final_kernel(
    const float* __restrict__ G,
    const float* __restrict__ rW2, const float* __restrict__ rb2,
    float* __restrict__ out) {
  int b = blockIdx.x;
  int t = threadIdx.x;
  __shared__ float4 Gs[64];
  __shared__ float T[256];
  if (t < 64) Gs[t] = ((const float4*)(G + b * 256))[t];
  __syncthreads();
  float acc = 256.f * rb2[t];
#pragma unroll 4
  for (int h4 = 0; h4 < 64; ++h4) {
    float4 gg = Gs[h4];
    acc = fmaf(gg.x, rW2[(h4 * 4 + 0) * 256 + t], acc);
    acc = fmaf(gg.y, rW2[(h4 * 4 + 1) * 256 + t], acc);
    acc = fmaf(gg.z, rW2[(h4 * 4 + 2) * 256 + t], acc);
    acc = fmaf(gg.w, rW2[(h4 * 4 + 3) * 256 + t], acc);
  }
  T[t] = acc * (1.f / 256.f);
  __syncthreads();
  int k = t >> 4, lcol = t & 15;
  out[b * 256 + t] = 0.5f * (T[k * 16 + lcol] + T[lcol * 16 + k]);
}

extern "C" void kernel_launch(void* const* d_in, const int* in_sizes, int n_in,
                              void* d_out, int out_size, void* d_ws, size_t ws_size,
                              hipStream_t stream) {
  const float* points = (const float*)d_in[0];
  const float* mW1 = (const float*)d_in[1];
  const float* mb1 = (const float*)d_in[2];
  const float* mW2 = (const float*)d_in[3];
  const float* mb2 = (const float*)d_in[4];
  const float* cW1 = (const float*)d_in[5];
  const float* cb1 = (const float*)d_in[6];
  const float* cW2 = (const float*)d_in[7];
  const float* cb2 = (const float*)d_in[8];
  const float* rW1 = (const float*)d_in[9];
  const float* rb1 = (const float*)d_in[10];
  const float* rW2 = (const float*)d_in[11];
  const float* rb2 = (const float*)d_in[12];
  float* out = (float*)d_out;

  float* ws = (float*)d_ws;
  float* metric = ws;                 // 65536
  float* A1 = metric + 65536;         // 65536
  float* Mi = A1 + 65536;             // 1048576
  float* Mj = Mi + 1048576;           // 1048576
  float* G = Mj + 1048576;            // 65536
  float* cwPackF = G + 65536;         // 512 (128 x float4)
  float* w2c = cwPackF + 512;         // 128
  float* tanhtab = w2c + 128;         // 1024 (512 x {slope, icpt})

  metric_proj_kernel<<<BATCH, 256, 0, stream>>>(
      points, mW1, mb1, mW2, mb2, rW1, rb1, cW1, cb1, cW2,
      metric, A1, Mi, Mj, G, (float4*)cwPackF, w2c, tanhtab);
  chr_kernel<<<BATCH * NDIM, 128, 0, stream>>>(metric, (const float4*)cwPackF,
                                               w2c, cb2, rW1, A1, Mi, Mj,
                                               tanhtab, G);
  final_kernel<<<BATCH, 256, 0, stream>>>(G, rW2, rb2, out);
}